// Round 1
// baseline (5490.361 us; speedup 1.0000x reference)
//
#include <hip/hip_runtime.h>
#include <math.h>

#define TM 64
#define TN 64
#define TK 16

// Implicit-GEMM conv: Y[n][co][p] = bias[co] + sum_k Wt[co][k] * im2col(X)[k][p]
// TAPS=1: 1x1 conv (k = ci). TAPS=9: 3x3 conv pad=1 (k = ci*9 + (ky*3+kx)).
// Cout is always 256 in this problem.
template<int TAPS>
__global__ __launch_bounds__(256) void conv_gemm(
    const float* __restrict__ X, const float* __restrict__ Wt,
    const float* __restrict__ bias, float* __restrict__ Y,
    int Cin, int H, int Wd)
{
    const int HW   = H * Wd;
    const int Ktot = Cin * TAPS;
    const int n    = blockIdx.z;
    const int p0   = blockIdx.x * TN;
    const int m0   = blockIdx.y * TM;
    const float* Xn = X + (size_t)n * Cin * HW;
    float* Yn       = Y + (size_t)n * 256 * HW;
    const int tid = threadIdx.x;

    __shared__ __align__(16) float As[TK][TM + 4];
    __shared__ __align__(16) float Bs[TK][TN + 4];

    // B-load mapping: 64 pixels x 4 k-rows per iteration
    const int bp  = tid & 63;
    const int bk0 = tid >> 6;       // 0..3
    const int q   = p0 + bp;
    const bool qin = q < HW;
    int qy = 0, qx = 0;
    if (TAPS == 9) { qy = q / Wd; qx = q - qy * Wd; }

    // A-load mapping: 16 k x 16 m per iteration (coalesced over k)
    const int ak  = tid & 15;
    const int am0 = tid >> 4;       // 0..15

    const int tx4 = (tid & 15) * 4;
    const int ty4 = (tid >> 4) * 4;

    float acc[4][4];
    #pragma unroll
    for (int i = 0; i < 4; ++i)
        #pragma unroll
        for (int j = 0; j < 4; ++j) acc[i][j] = 0.f;

    for (int k0 = 0; k0 < Ktot; k0 += TK) {
        #pragma unroll
        for (int it = 0; it < 1; ++it) {
            As[ak][am0]      = Wt[(size_t)(m0 + am0) * Ktot + (k0 + ak)];
            As[ak][am0 + 16] = Wt[(size_t)(m0 + am0 + 16) * Ktot + (k0 + ak)];
            As[ak][am0 + 32] = Wt[(size_t)(m0 + am0 + 32) * Ktot + (k0 + ak)];
            As[ak][am0 + 48] = Wt[(size_t)(m0 + am0 + 48) * Ktot + (k0 + ak)];
        }
        #pragma unroll
        for (int it = 0; it < 4; ++it) {
            int krow = bk0 + it * 4;
            int kg = k0 + krow;
            float v = 0.f;
            if (TAPS == 1) {
                if (qin) v = Xn[(size_t)kg * HW + q];
            } else {
                int ci  = kg / 9;
                int tap = kg - ci * 9;
                int t3  = tap / 3;
                int dy  = t3 - 1;
                int dx  = tap - t3 * 3 - 1;
                int yy = qy + dy, xx = qx + dx;
                if (qin && yy >= 0 && yy < H && xx >= 0 && xx < Wd)
                    v = Xn[(size_t)ci * HW + yy * Wd + xx];
            }
            Bs[krow][bp] = v;
        }
        __syncthreads();
        #pragma unroll
        for (int kk = 0; kk < TK; ++kk) {
            float4 a4 = *(const float4*)&As[kk][ty4];
            float4 b4 = *(const float4*)&Bs[kk][tx4];
            float av[4] = {a4.x, a4.y, a4.z, a4.w};
            float bv[4] = {b4.x, b4.y, b4.z, b4.w};
            #pragma unroll
            for (int i = 0; i < 4; ++i)
                #pragma unroll
                for (int j = 0; j < 4; ++j)
                    acc[i][j] = fmaf(av[i], bv[j], acc[i][j]);
        }
        __syncthreads();
    }

    #pragma unroll
    for (int i = 0; i < 4; ++i) {
        int m = m0 + ty4 + i;
        float bi = bias[m];
        #pragma unroll
        for (int j = 0; j < 4; ++j) {
            int qq = p0 + tx4 + j;
            if (qq < HW) Yn[(size_t)m * HW + qq] = acc[i][j] + bi;
        }
    }
}

// T (at [.,C,H,W]) += bilinear_upsample2x(Pn at [.,C,H/2,W/2]) — jax.image.resize
// 'bilinear' semantics: half-pixel centers, edge weights renormalize == clamp.
__global__ void upsample_add_k(float* __restrict__ T, const float* __restrict__ Pn,
                               int H, int Wd, int total)
{
    const int Hh = H >> 1, Wh = Wd >> 1;
    for (int i = blockIdx.x * blockDim.x + threadIdx.x; i < total;
         i += gridDim.x * blockDim.x) {
        int x  = i % Wd;
        int t1 = i / Wd;
        int y  = t1 % H;
        int nc = t1 / H;
        float sy = fminf(fmaxf(y * 0.5f - 0.25f, 0.f), (float)(Hh - 1));
        float sx = fminf(fmaxf(x * 0.5f - 0.25f, 0.f), (float)(Wh - 1));
        int y0 = (int)sy, x0 = (int)sx;
        int y1 = min(y0 + 1, Hh - 1), x1 = min(x0 + 1, Wh - 1);
        float fy = sy - (float)y0, fx = sx - (float)x0;
        const float* f = Pn + (size_t)nc * Hh * Wh;
        float v = (1.f - fy) * ((1.f - fx) * f[y0 * Wh + x0] + fx * f[y0 * Wh + x1])
                +        fy  * ((1.f - fx) * f[y1 * Wh + x0] + fx * f[y1 * Wh + x1]);
        T[i] += v;
    }
}

// One block per roi (256 threads = 256 channels). Exact replication of the
// reference roi_align (aligned=false, SAMP=2, P=7) incl. validity mask.
__global__ __launch_bounds__(256) void roi_align_k(
    const float* __restrict__ rois, const float* __restrict__ im_info,
    const float* __restrict__ p2, const float* __restrict__ p3,
    const float* __restrict__ p4, const float* __restrict__ p5,
    float* __restrict__ out)
{
    const int r   = blockIdx.x;
    const int tid = threadIdx.x;

    __shared__ int   s_y0[14], s_y1[14], s_x0[14], s_x1[14];
    __shared__ float s_ly[14], s_lx[14], s_vy[14], s_vx[14];

    const float bx  = rois[r * 5 + 0];
    const float x1r = rois[r * 5 + 1];
    const float y1r = rois[r * 5 + 2];
    const float x2r = rois[r * 5 + 3];
    const float y2r = rois[r * 5 + 4];

    const float hh = y2r - y1r + 1.f;
    const float ww = x2r - x1r + 1.f;
    float lf = rintf(logf(sqrtf(hh * ww) * (1.f / 224.f)) + 4.f);
    lf = fminf(fmaxf(lf, 2.f), 5.f);
    const int lvl = (int)lf;

    const float* feat; int H, W;
    if      (lvl == 2) { feat = p2; H = 200; W = 304; }
    else if (lvl == 3) { feat = p3; H = 100; W = 152; }
    else if (lvl == 4) { feat = p4; H = 50;  W = 76;  }
    else               { feat = p5; H = 25;  W = 38;  }

    const float im_h  = im_info[0];
    const float scale = (float)H / im_h;
    const float x1 = x1r * scale, y1 = y1r * scale;
    const float x2 = x2r * scale, y2 = y2r * scale;
    const float rw = fmaxf(x2 - x1, 1.f);
    const float rh = fmaxf(y2 - y1, 1.f);
    const float bh = rh * (1.f / 7.f);
    const float bw = rw * (1.f / 7.f);

    if (tid < 28) {
        if (tid < 14) {
            int i = tid, pi = i >> 1, s = i & 1;
            float ys = y1 + pi * bh + (s + 0.5f) * bh * 0.5f;
            float v  = (ys >= -1.f && ys <= (float)H) ? 1.f : 0.f;
            float yc = fminf(fmaxf(ys, 0.f), (float)H - 1.f);
            int y0 = (int)floorf(yc);
            s_y0[i] = y0;
            s_y1[i] = min(y0 + 1, H - 1);
            s_ly[i] = yc - (float)y0;
            s_vy[i] = v;
        } else {
            int i = tid - 14, pi = i >> 1, s = i & 1;
            float xs = x1 + pi * bw + (s + 0.5f) * bw * 0.5f;
            float v  = (xs >= -1.f && xs <= (float)W) ? 1.f : 0.f;
            float xc = fminf(fmaxf(xs, 0.f), (float)W - 1.f);
            int x0 = (int)floorf(xc);
            s_x0[i] = x0;
            s_x1[i] = min(x0 + 1, W - 1);
            s_lx[i] = xc - (float)x0;
            s_vx[i] = v;
        }
    }
    __syncthreads();

    const int b = (int)bx;
    const float* fc = feat + ((size_t)b * 256 + tid) * (size_t)(H * W);
    float* oc = out + ((size_t)r * 256 + tid) * 49;

    #pragma unroll
    for (int py = 0; py < 7; ++py) {
        #pragma unroll
        for (int px = 0; px < 7; ++px) {
            float acc = 0.f;
            #pragma unroll
            for (int sy = 0; sy < 2; ++sy) {
                #pragma unroll
                for (int sx = 0; sx < 2; ++sx) {
                    int iy = py * 2 + sy, ix = px * 2 + sx;
                    float ly = s_ly[iy], lx = s_lx[ix];
                    float hy = 1.f - ly, hx = 1.f - lx;
                    int y0 = s_y0[iy], y1i = s_y1[iy];
                    int x0 = s_x0[ix], x1i = s_x1[ix];
                    float v00 = fc[y0 * W + x0],  v01 = fc[y0 * W + x1i];
                    float v10 = fc[y1i * W + x0], v11 = fc[y1i * W + x1i];
                    float val = hy * hx * v00 + hy * lx * v01
                              + ly * hx * v10 + ly * lx * v11;
                    acc += val * s_vy[iy] * s_vx[ix];
                }
            }
            oc[py * 7 + px] = acc * 0.25f;
        }
    }
}

static inline int cdiv(int a, int b) { return (a + b - 1) / b; }

extern "C" void kernel_launch(void* const* d_in, const int* in_sizes, int n_in,
                              void* d_out, int out_size, void* d_ws, size_t ws_size,
                              hipStream_t stream) {
    const float* c2      = (const float*)d_in[0];
    const float* c3      = (const float*)d_in[1];
    const float* c4      = (const float*)d_in[2];
    const float* c5      = (const float*)d_in[3];
    const float* rois    = (const float*)d_in[4];
    const float* im_info = (const float*)d_in[5];
    const float* w_top   = (const float*)d_in[6];
    const float* b_top   = (const float*)d_in[7];
    const float* w_lat1  = (const float*)d_in[8];
    const float* b_lat1  = (const float*)d_in[9];
    const float* w_lat2  = (const float*)d_in[10];
    const float* b_lat2  = (const float*)d_in[11];
    const float* w_lat3  = (const float*)d_in[12];
    const float* b_lat3  = (const float*)d_in[13];
    const float* w_sm1   = (const float*)d_in[14];
    const float* b_sm1   = (const float*)d_in[15];
    const float* w_sm2   = (const float*)d_in[16];
    const float* b_sm2   = (const float*)d_in[17];
    const float* w_sm3   = (const float*)d_in[18];
    const float* b_sm3   = (const float*)d_in[19];
    float* out = (float*)d_out;
    float* ws  = (float*)d_ws;

    // Workspace layout (floats): p5 | p4 | p3 | p2 | T(scratch t/u)
    float* p5 = ws;                    // 2*256*25*38   = 486400
    float* p4 = p5 + 486400;           // 2*256*50*76   = 1945600
    float* p3 = p4 + 1945600;          // 2*256*100*152 = 7782400
    float* p2 = p3 + 7782400;          // 2*256*200*304 = 31129600
    float* T  = p2 + 31129600;         // max t/u size  = 31129600

    dim3 blk(256);

    // p5 = conv1x1(c5, w_top) + b_top
    conv_gemm<1><<<dim3(cdiv(950, TN), 4, 2), blk, 0, stream>>>(
        c5, w_top, b_top, p5, 2048, 25, 38);

    // level 4: t4 = conv1x1(c4, w_lat1); u4 = t4 + up(p5); p4 = conv3x3(u4, w_sm1)
    conv_gemm<1><<<dim3(cdiv(3800, TN), 4, 2), blk, 0, stream>>>(
        c4, w_lat1, b_lat1, T, 1024, 50, 76);
    upsample_add_k<<<cdiv(2 * 256 * 3800, 256), blk, 0, stream>>>(
        T, p5, 50, 76, 2 * 256 * 3800);
    conv_gemm<9><<<dim3(cdiv(3800, TN), 4, 2), blk, 0, stream>>>(
        T, w_sm1, b_sm1, p4, 256, 50, 76);

    // level 3
    conv_gemm<1><<<dim3(cdiv(15200, TN), 4, 2), blk, 0, stream>>>(
        c3, w_lat2, b_lat2, T, 512, 100, 152);
    upsample_add_k<<<cdiv(2 * 256 * 15200, 256), blk, 0, stream>>>(
        T, p4, 100, 152, 2 * 256 * 15200);
    conv_gemm<9><<<dim3(cdiv(15200, TN), 4, 2), blk, 0, stream>>>(
        T, w_sm2, b_sm2, p3, 256, 100, 152);

    // level 2
    conv_gemm<1><<<dim3(cdiv(60800, TN), 4, 2), blk, 0, stream>>>(
        c2, w_lat3, b_lat3, T, 256, 200, 304);
    upsample_add_k<<<cdiv(2 * 256 * 60800, 256), blk, 0, stream>>>(
        T, p3, 200, 304, 2 * 256 * 60800);
    conv_gemm<9><<<dim3(cdiv(60800, TN), 4, 2), blk, 0, stream>>>(
        T, w_sm3, b_sm3, p2, 256, 200, 304);

    // roi align + level select
    roi_align_k<<<dim3(1024), blk, 0, stream>>>(
        rois, im_info, p2, p3, p4, p5, out);
}

// Round 2
// 1235.003 us; speedup vs baseline: 4.4456x; 4.4456x over previous
//
#include <hip/hip_runtime.h>
#include <math.h>

typedef __attribute__((ext_vector_type(8))) short short8;
typedef __attribute__((ext_vector_type(4))) float f32x4;
typedef __attribute__((ext_vector_type(8))) unsigned short ushort8v;

__device__ __forceinline__ ushort f2bf(float f) {
    unsigned u = __builtin_bit_cast(unsigned, f);
    u = (u + 0x7fffu + ((u >> 16) & 1u)) >> 16;
    return (ushort)u;
}
__device__ __forceinline__ float bf2f(ushort h) {
    unsigned u = ((unsigned)h) << 16;
    return __builtin_bit_cast(float, u);
}

// ---------------- cast / pack kernels ----------------

// NCHW f32 -> NHWC bf16 (per n: transpose C x HW -> HW x C)
__global__ void nchw2nhwc(const float* __restrict__ in, ushort* __restrict__ out,
                          int C, int HW)
{
    __shared__ float tile[32][33];
    const int n  = blockIdx.z;
    const int c0 = blockIdx.y * 32;
    const int p0 = blockIdx.x * 32;
    const float* inp = in + (size_t)n * C * HW;
    ushort* op = out + (size_t)n * HW * C;
    const int tx = threadIdx.x & 31, ty = threadIdx.x >> 5;  // ty 0..7
    #pragma unroll
    for (int i = 0; i < 4; ++i) {
        int c = ty + i * 8;
        int p = p0 + tx;
        tile[c][tx] = (p < HW) ? inp[(size_t)(c0 + c) * HW + p] : 0.f;
    }
    __syncthreads();
    #pragma unroll
    for (int i = 0; i < 4; ++i) {
        int p = ty + i * 8;
        if (p0 + p < HW) op[(size_t)(p0 + p) * C + c0 + tx] = f2bf(tile[tx][p]);
    }
}

// f32 -> bf16 elementwise (1x1 weights: layout already [co][ci])
__global__ void cast_k(const float* __restrict__ in, ushort* __restrict__ out, int n)
{
    int i = blockIdx.x * 256 + threadIdx.x;
    if (i < n) out[i] = f2bf(in[i]);
}

// 3x3 weights OIHW f32 -> [co][tap][ci] bf16 (tap-major K)
__global__ void pack_w3(const float* __restrict__ w, ushort* __restrict__ wp, int Cin)
{
    int i = blockIdx.x * 256 + threadIdx.x;
    int total = 256 * Cin * 9;
    if (i >= total) return;
    int co  = i / (9 * Cin);
    int rem = i - co * 9 * Cin;
    int tap = rem / Cin;
    int ci  = rem - tap * Cin;
    wp[i] = f2bf(w[(size_t)co * Cin * 9 + (size_t)ci * 9 + tap]);
}

// ---------------- MFMA conv (implicit GEMM, NHWC bf16) ----------------
// Y[n][q][co] = bias[co] + sum_k Wp[co][k] * im2col(X)[k][q]
// TAPS=1: k=ci. TAPS=9: k=tap*Cin+ci (Cin must be 256 for TAPS=9).
template<int TAPS>
__global__ __launch_bounds__(256, 2) void conv_mfma(
    const ushort* __restrict__ X, const ushort* __restrict__ Wp,
    const float* __restrict__ bias, ushort* __restrict__ Y,
    int Cin, int H, int Wd)
{
    const int HW   = H * Wd;
    const int Ktot = Cin * TAPS;
    const int n    = blockIdx.z;
    const int p0   = blockIdx.x * 128;
    const int m0   = blockIdx.y * 128;
    const ushort* Xn = X + (size_t)n * HW * Cin;
    ushort* Yn       = Y + (size_t)n * HW * 256;

    const int t   = threadIdx.x;
    const int lid = t & 63;
    const int wv  = t >> 6;
    const int wm  = (wv >> 1) * 64, wn = (wv & 1) * 64;
    const int l15 = lid & 15, lq = lid >> 4;

    __shared__ __align__(16) ushort As[128 * 40];
    __shared__ __align__(16) ushort Bs[128 * 40];

    const int r0 = t >> 2;         // staging row 0..63 (+64 on pass 1)
    const int kq = (t & 3) * 8;    // k sub-offset 0,8,16,24

    int q_[2], qy_[2], qx_[2];
    bool qin_[2];
    #pragma unroll
    for (int i = 0; i < 2; ++i) {
        int q = p0 + r0 + i * 64;
        q_[i] = q;
        qin_[i] = q < HW;
        if (TAPS == 9) { int y = q / Wd; qy_[i] = y; qx_[i] = q - y * Wd; }
    }

    f32x4 acc[4][4] = {};

    const int nch = Ktot / 32;
    for (int kc = 0; kc < nch; ++kc) {
        const int k0 = kc * 32;
        #pragma unroll
        for (int i = 0; i < 2; ++i) {
            int row = r0 + i * 64;
            uint4 v = *(const uint4*)&Wp[(size_t)(m0 + row) * Ktot + k0 + kq];
            *(uint4*)&As[row * 40 + kq] = v;
        }
        int dy = 0, dx = 0, cb = k0;
        if (TAPS == 9) {
            int tap = kc >> 3;          // Cin == 256
            cb = (kc & 7) * 32;
            dy = tap / 3 - 1;
            dx = tap - (tap / 3) * 3 - 1;
        }
        #pragma unroll
        for (int i = 0; i < 2; ++i) {
            int row = r0 + i * 64;
            uint4 v = {0u, 0u, 0u, 0u};
            if (TAPS == 1) {
                if (qin_[i]) v = *(const uint4*)&Xn[(size_t)q_[i] * Cin + k0 + kq];
            } else {
                int yy = qy_[i] + dy, xx = qx_[i] + dx;
                if (qin_[i] && yy >= 0 && yy < H && xx >= 0 && xx < Wd)
                    v = *(const uint4*)&Xn[(size_t)(yy * Wd + xx) * Cin + cb + kq];
            }
            *(uint4*)&Bs[row * 40 + kq] = v;
        }
        __syncthreads();

        short8 af[4], bfr[4];
        #pragma unroll
        for (int mi = 0; mi < 4; ++mi)
            af[mi] = *(const short8*)&As[(wm + mi * 16 + l15) * 40 + lq * 8];
        #pragma unroll
        for (int ni = 0; ni < 4; ++ni)
            bfr[ni] = *(const short8*)&Bs[(wn + ni * 16 + l15) * 40 + lq * 8];
        #pragma unroll
        for (int mi = 0; mi < 4; ++mi)
            #pragma unroll
            for (int ni = 0; ni < 4; ++ni)
                acc[mi][ni] = __builtin_amdgcn_mfma_f32_16x16x32_bf16(
                    af[mi], bfr[ni], acc[mi][ni], 0, 0, 0);
        __syncthreads();
    }

    #pragma unroll
    for (int mi = 0; mi < 4; ++mi) {
        int co = wm + mi * 16 + lq * 4;                 // within m-tile
        float4 bv = *(const float4*)&bias[m0 + co];
        float bb[4] = {bv.x, bv.y, bv.z, bv.w};
        #pragma unroll
        for (int ni = 0; ni < 4; ++ni) {
            int q = p0 + wn + ni * 16 + l15;
            if (q < HW) {
                ushort4 h;
                h.x = f2bf(acc[mi][ni][0] + bb[0]);
                h.y = f2bf(acc[mi][ni][1] + bb[1]);
                h.z = f2bf(acc[mi][ni][2] + bb[2]);
                h.w = f2bf(acc[mi][ni][3] + bb[3]);
                *(ushort4*)&Yn[(size_t)q * 256 + m0 + co] = h;
            }
        }
    }
}

// ---------------- upsample(2x bilinear, half-pixel, clamp) + add, NHWC bf16 ----
__global__ void upsample_add_nhwc(ushort* __restrict__ T, const ushort* __restrict__ Pn,
                                  int H, int Wd, int total32)
{
    int i = blockIdx.x * 256 + threadIdx.x;
    if (i >= total32) return;
    const int cg = (i & 31) * 8;        // channel offset
    const int q  = i >> 5;              // n*HW + pix
    const int HW = H * Wd;
    const int pix = q % HW;
    const int n   = q / HW;
    const int y = pix / Wd, x = pix - (pix / Wd) * Wd;
    const int Hh = H >> 1, Wh = Wd >> 1;

    float sy = fminf(fmaxf(y * 0.5f - 0.25f, 0.f), (float)(Hh - 1));
    float sx = fminf(fmaxf(x * 0.5f - 0.25f, 0.f), (float)(Wh - 1));
    int y0 = (int)sy, x0 = (int)sx;
    int y1 = min(y0 + 1, Hh - 1), x1 = min(x0 + 1, Wh - 1);
    float fy = sy - (float)y0, fx = sx - (float)x0;

    const ushort* base = Pn + (size_t)n * Hh * Wh * 256 + cg;
    ushort8v a00 = *(const ushort8v*)&base[(size_t)(y0 * Wh + x0) * 256];
    ushort8v a01 = *(const ushort8v*)&base[(size_t)(y0 * Wh + x1) * 256];
    ushort8v a10 = *(const ushort8v*)&base[(size_t)(y1 * Wh + x0) * 256];
    ushort8v a11 = *(const ushort8v*)&base[(size_t)(y1 * Wh + x1) * 256];

    ushort* tp = T + (size_t)q * 256 + cg;
    ushort8v tv = *(ushort8v*)tp;
    ushort8v r;
    #pragma unroll
    for (int j = 0; j < 8; ++j) {
        float v = (1.f - fy) * ((1.f - fx) * bf2f(a00[j]) + fx * bf2f(a01[j]))
                +        fy  * ((1.f - fx) * bf2f(a10[j]) + fx * bf2f(a11[j]));
        r[j] = f2bf(bf2f(tv[j]) + v);
    }
    *(ushort8v*)tp = r;
}

// ---------------- roi align (NHWC bf16 feats, f32 out) ----------------
__global__ __launch_bounds__(256) void roi_align_k(
    const float* __restrict__ rois, const float* __restrict__ im_info,
    const ushort* __restrict__ p2, const ushort* __restrict__ p3,
    const ushort* __restrict__ p4, const ushort* __restrict__ p5,
    float* __restrict__ out)
{
    const int r   = blockIdx.x;
    const int tid = threadIdx.x;

    __shared__ int   s_y0[14], s_y1[14], s_x0[14], s_x1[14];
    __shared__ float s_ly[14], s_lx[14], s_vy[14], s_vx[14];
    __shared__ float s_o[256 * 49];

    const float bx  = rois[r * 5 + 0];
    const float x1r = rois[r * 5 + 1];
    const float y1r = rois[r * 5 + 2];
    const float x2r = rois[r * 5 + 3];
    const float y2r = rois[r * 5 + 4];

    const float hh = y2r - y1r + 1.f;
    const float ww = x2r - x1r + 1.f;
    float lf = rintf(logf(sqrtf(hh * ww) * (1.f / 224.f)) + 4.f);
    lf = fminf(fmaxf(lf, 2.f), 5.f);
    const int lvl = (int)lf;

    const ushort* feat; int H, W;
    if      (lvl == 2) { feat = p2; H = 200; W = 304; }
    else if (lvl == 3) { feat = p3; H = 100; W = 152; }
    else if (lvl == 4) { feat = p4; H = 50;  W = 76;  }
    else               { feat = p5; H = 25;  W = 38;  }

    const float im_h  = im_info[0];
    const float scale = (float)H / im_h;
    const float x1 = x1r * scale, y1 = y1r * scale;
    const float x2 = x2r * scale, y2 = y2r * scale;
    const float rw = fmaxf(x2 - x1, 1.f);
    const float rh = fmaxf(y2 - y1, 1.f);
    const float bh = rh * (1.f / 7.f);
    const float bw = rw * (1.f / 7.f);

    if (tid < 28) {
        if (tid < 14) {
            int i = tid, pi = i >> 1, s = i & 1;
            float ys = y1 + pi * bh + (s + 0.5f) * bh * 0.5f;
            float v  = (ys >= -1.f && ys <= (float)H) ? 1.f : 0.f;
            float yc = fminf(fmaxf(ys, 0.f), (float)H - 1.f);
            int y0 = (int)floorf(yc);
            s_y0[i] = y0; s_y1[i] = min(y0 + 1, H - 1);
            s_ly[i] = yc - (float)y0; s_vy[i] = v;
        } else {
            int i = tid - 14, pi = i >> 1, s = i & 1;
            float xs = x1 + pi * bw + (s + 0.5f) * bw * 0.5f;
            float v  = (xs >= -1.f && xs <= (float)W) ? 1.f : 0.f;
            float xc = fminf(fmaxf(xs, 0.f), (float)W - 1.f);
            int x0 = (int)floorf(xc);
            s_x0[i] = x0; s_x1[i] = min(x0 + 1, W - 1);
            s_lx[i] = xc - (float)x0; s_vx[i] = v;
        }
    }
    __syncthreads();

    const int b = (int)bx;
    const ushort* fc = feat + (size_t)b * H * W * 256 + tid;

    #pragma unroll
    for (int py = 0; py < 7; ++py) {
        #pragma unroll
        for (int px = 0; px < 7; ++px) {
            float acc = 0.f;
            #pragma unroll
            for (int sy = 0; sy < 2; ++sy) {
                #pragma unroll
                for (int sx = 0; sx < 2; ++sx) {
                    int iy = py * 2 + sy, ix = px * 2 + sx;
                    float ly = s_ly[iy], lx = s_lx[ix];
                    float hy = 1.f - ly, hx = 1.f - lx;
                    int y0 = s_y0[iy], y1i = s_y1[iy];
                    int x0 = s_x0[ix], x1i = s_x1[ix];
                    float v00 = bf2f(fc[(size_t)(y0 * W + x0) * 256]);
                    float v01 = bf2f(fc[(size_t)(y0 * W + x1i) * 256]);
                    float v10 = bf2f(fc[(size_t)(y1i * W + x0) * 256]);
                    float v11 = bf2f(fc[(size_t)(y1i * W + x1i) * 256]);
                    float val = hy * hx * v00 + hy * lx * v01
                              + ly * hx * v10 + ly * lx * v11;
                    acc += val * s_vy[iy] * s_vx[ix];
                }
            }
            s_o[tid * 49 + py * 7 + px] = acc * 0.25f;
        }
    }
    __syncthreads();
    // coalesced copy-out: out[r][c][49] flat == s_o flat
    float* orow = out + (size_t)r * 256 * 49;
    for (int it = 0; it < 49; ++it)
        orow[it * 256 + tid] = s_o[it * 256 + tid];
}

static inline int cdiv(int a, int b) { return (a + b - 1) / b; }

extern "C" void kernel_launch(void* const* d_in, const int* in_sizes, int n_in,
                              void* d_out, int out_size, void* d_ws, size_t ws_size,
                              hipStream_t stream) {
    const float* c2      = (const float*)d_in[0];
    const float* c3      = (const float*)d_in[1];
    const float* c4      = (const float*)d_in[2];
    const float* c5      = (const float*)d_in[3];
    const float* rois    = (const float*)d_in[4];
    const float* im_info = (const float*)d_in[5];
    const float* w_top   = (const float*)d_in[6];
    const float* b_top   = (const float*)d_in[7];
    const float* w_lat1  = (const float*)d_in[8];
    const float* b_lat1  = (const float*)d_in[9];
    const float* w_lat2  = (const float*)d_in[10];
    const float* b_lat2  = (const float*)d_in[11];
    const float* w_lat3  = (const float*)d_in[12];
    const float* b_lat3  = (const float*)d_in[13];
    const float* w_sm1   = (const float*)d_in[14];
    const float* b_sm1   = (const float*)d_in[15];
    const float* w_sm2   = (const float*)d_in[16];
    const float* b_sm2   = (const float*)d_in[17];
    const float* w_sm3   = (const float*)d_in[18];
    const float* b_sm3   = (const float*)d_in[19];
    float* out = (float*)d_out;
    ushort* ws = (ushort*)d_ws;

    // workspace layout (bf16 elements, all offsets 16B-aligned)
    ushort* c2t = ws;                      // 2*60800*256 = 31129600
    ushort* c3t = c2t + 31129600;          // 2*15200*512 = 15564800
    ushort* c4t = c3t + 15564800;          // 2*3800*1024 = 7782400
    ushort* c5t = c4t + 7782400;           // 2*950*2048  = 3891200
    ushort* p5  = c5t + 3891200;           // 2*950*256   = 486400
    ushort* p4  = p5  + 486400;            // 2*3800*256  = 1945600
    ushort* p3  = p4  + 1945600;           // 2*15200*256 = 7782400
    ushort* p2  = p3  + 7782400;           // 2*60800*256 = 31129600
    ushort* T   = p2  + 31129600;          // scratch     = 31129600
    ushort* wtp = T   + 31129600;          // 256*2048
    ushort* wl1 = wtp + 524288;            // 256*1024
    ushort* wl2 = wl1 + 262144;            // 256*512
    ushort* wl3 = wl2 + 131072;            // 256*256
    ushort* ws1 = wl3 + 65536;             // 256*2304
    ushort* ws2 = ws1 + 589824;
    ushort* ws3 = ws2 + 589824;

    dim3 blk(256);

    // pack weights
    cast_k<<<cdiv(524288, 256), blk, 0, stream>>>(w_top,  wtp, 524288);
    cast_k<<<cdiv(262144, 256), blk, 0, stream>>>(w_lat1, wl1, 262144);
    cast_k<<<cdiv(131072, 256), blk, 0, stream>>>(w_lat2, wl2, 131072);
    cast_k<<<cdiv(65536,  256), blk, 0, stream>>>(w_lat3, wl3, 65536);
    pack_w3<<<cdiv(589824, 256), blk, 0, stream>>>(w_sm1, ws1, 256);
    pack_w3<<<cdiv(589824, 256), blk, 0, stream>>>(w_sm2, ws2, 256);
    pack_w3<<<cdiv(589824, 256), blk, 0, stream>>>(w_sm3, ws3, 256);

    // transpose inputs to NHWC bf16
    nchw2nhwc<<<dim3(1900, 8,  2), blk, 0, stream>>>(c2, c2t, 256,  60800);
    nchw2nhwc<<<dim3(475, 16,  2), blk, 0, stream>>>(c3, c3t, 512,  15200);
    nchw2nhwc<<<dim3(119, 32,  2), blk, 0, stream>>>(c4, c4t, 1024, 3800);
    nchw2nhwc<<<dim3(30,  64,  2), blk, 0, stream>>>(c5, c5t, 2048, 950);

    // p5 = conv1x1(c5)
    conv_mfma<1><<<dim3(8, 2, 2), blk, 0, stream>>>(c5t, wtp, b_top, p5, 2048, 25, 38);

    // level 4
    conv_mfma<1><<<dim3(30, 2, 2), blk, 0, stream>>>(c4t, wl1, b_lat1, T, 1024, 50, 76);
    upsample_add_nhwc<<<cdiv(2 * 3800 * 32, 256), blk, 0, stream>>>(T, p5, 50, 76, 2 * 3800 * 32);
    conv_mfma<9><<<dim3(30, 2, 2), blk, 0, stream>>>(T, ws1, b_sm1, p4, 256, 50, 76);

    // level 3
    conv_mfma<1><<<dim3(119, 2, 2), blk, 0, stream>>>(c3t, wl2, b_lat2, T, 512, 100, 152);
    upsample_add_nhwc<<<cdiv(2 * 15200 * 32, 256), blk, 0, stream>>>(T, p4, 100, 152, 2 * 15200 * 32);
    conv_mfma<9><<<dim3(119, 2, 2), blk, 0, stream>>>(T, ws2, b_sm2, p3, 256, 100, 152);

    // level 2
    conv_mfma<1><<<dim3(475, 2, 2), blk, 0, stream>>>(c2t, wl3, b_lat3, T, 256, 200, 304);
    upsample_add_nhwc<<<cdiv(2 * 60800 * 32, 256), blk, 0, stream>>>(T, p3, 200, 304, 2 * 60800 * 32);
    conv_mfma<9><<<dim3(475, 2, 2), blk, 0, stream>>>(T, ws3, b_sm3, p2, 256, 200, 304);

    // roi align
    roi_align_k<<<dim3(1024), blk, 0, stream>>>(rois, im_info, p2, p3, p4, p5, out);
}

// Round 3
// 1208.977 us; speedup vs baseline: 4.5413x; 1.0215x over previous
//
#include <hip/hip_runtime.h>
#include <math.h>

typedef __attribute__((ext_vector_type(8))) short short8;
typedef __attribute__((ext_vector_type(4))) float f32x4;
typedef __attribute__((ext_vector_type(8))) unsigned short ushort8v;

__device__ __forceinline__ ushort f2bf(float f) {
    unsigned u = __builtin_bit_cast(unsigned, f);
    u = (u + 0x7fffu + ((u >> 16) & 1u)) >> 16;
    return (ushort)u;
}
__device__ __forceinline__ float bf2f(ushort h) {
    unsigned u = ((unsigned)h) << 16;
    return __builtin_bit_cast(float, u);
}

// async 16B global->LDS: lane's data lands at ldsbase + lane*16
__device__ __forceinline__ void gl_lds16(const ushort* g, ushort* l) {
    __builtin_amdgcn_global_load_lds(
        (const __attribute__((address_space(1))) unsigned int*)g,
        (__attribute__((address_space(3))) unsigned int*)l, 16, 0, 0);
}

// ---------------- cast / pack kernels ----------------

__global__ void nchw2nhwc(const float* __restrict__ in, ushort* __restrict__ out,
                          int C, int HW)
{
    __shared__ float tile[32][33];
    const int n  = blockIdx.z;
    const int c0 = blockIdx.y * 32;
    const int p0 = blockIdx.x * 32;
    const float* inp = in + (size_t)n * C * HW;
    ushort* op = out + (size_t)n * HW * C;
    const int tx = threadIdx.x & 31, ty = threadIdx.x >> 5;
    #pragma unroll
    for (int i = 0; i < 4; ++i) {
        int c = ty + i * 8;
        int p = p0 + tx;
        tile[c][tx] = (p < HW) ? inp[(size_t)(c0 + c) * HW + p] : 0.f;
    }
    __syncthreads();
    #pragma unroll
    for (int i = 0; i < 4; ++i) {
        int p = ty + i * 8;
        if (p0 + p < HW) op[(size_t)(p0 + p) * C + c0 + tx] = f2bf(tile[tx][p]);
    }
}

__global__ void cast_k(const float* __restrict__ in, ushort* __restrict__ out, int n)
{
    int i = blockIdx.x * 256 + threadIdx.x;
    if (i < n) out[i] = f2bf(in[i]);
}

// 3x3 weights OIHW f32 -> [co][tap][ci] bf16 (tap-major K)
__global__ void pack_w3(const float* __restrict__ w, ushort* __restrict__ wp, int Cin)
{
    int i = blockIdx.x * 256 + threadIdx.x;
    int total = 256 * Cin * 9;
    if (i >= total) return;
    int co  = i / (9 * Cin);
    int rem = i - co * 9 * Cin;
    int tap = rem / Cin;
    int ci  = rem - tap * Cin;
    wp[i] = f2bf(w[(size_t)co * Cin * 9 + (size_t)ci * 9 + tap]);
}

// ---------------- MFMA conv (implicit GEMM, NHWC bf16) ----------------
// Block: 512 thr (8 waves), tile M=256 (all cout) x N=128 pixels, BK=32.
// Staging via global_load_lds(16B); LDS chunk layout chosen so that a wave's
// fragment ds_read_b128 is linear (base + lane*16) -> conflict-free.
// chunk j in tile = blk16*64 + lq*16 + l15  (blk16 = row/16, lq = kquad)
// TAPS==9: k-chunk order is (channel-chunk OUTER, tap INNER) for L2 reuse.
template<int TAPS>
__global__ __launch_bounds__(512, 4) void conv_mfma(
    const ushort* __restrict__ X, const ushort* __restrict__ Wp,
    const float* __restrict__ bias, ushort* __restrict__ Y,
    const ushort* __restrict__ zp,
    int Cin, int H, int Wd)
{
    const int HW   = H * Wd;
    const int Ktot = Cin * TAPS;
    const int n    = blockIdx.z;
    const int p0   = blockIdx.x * 128;
    const ushort* Xn = X + (size_t)n * HW * Cin;
    ushort* Yn       = Y + (size_t)n * HW * 256;

    const int t    = threadIdx.x;
    const int lane = t & 63;
    const int wave = t >> 6;            // 0..7
    const int l15  = lane & 15, lq = lane >> 4;
    const int kq8  = lq * 8;            // 16B chunk offset in k (shorts)

    __shared__ __align__(16) ushort As[8192];   // 256 rows x 32 k
    __shared__ __align__(16) ushort Bs[4096];   // 128 rows x 32 k

    // A staging: wave issues 2 instrs covering cout blocks (wave*2, wave*2+1)
    const ushort* ag0 = Wp + (size_t)(wave * 32 + l15) * Ktot + kq8;
    const ushort* ag1 = ag0 + (size_t)16 * Ktot;
    ushort* al0 = &As[(wave * 2 + 0) * 512];
    ushort* al1 = &As[(wave * 2 + 1) * 512];

    // B staging: wave issues 1 instr covering pixel block `wave`
    const int q   = p0 + wave * 16 + l15;
    const bool qin = q < HW;
    int qy = 0, qx = 0;
    if (TAPS == 9) { qy = q / Wd; qx = q - qy * Wd; }
    ushort* bl = &Bs[wave * 512];

    // fragment read bases (shorts); wave-linear -> conflict-free
    const int a_base = ((wave >> 1) * 256 + lq * 16 + l15) * 8;
    const int b_base = ((wave & 1) * 256 + lq * 16 + l15) * 8;

    f32x4 acc[4][4] = {};

    if (TAPS == 1) {
        const int nch = Cin >> 5;
        const ushort* bg_in = Xn + (size_t)q * Cin + kq8;
        for (int c = 0; c < nch; ++c) {
            const int k0 = c * 32;
            gl_lds16(ag0 + k0, al0);
            gl_lds16(ag1 + k0, al1);
            gl_lds16(qin ? (bg_in + k0) : zp, bl);
            __syncthreads();
            short8 af[4], bf[4];
            #pragma unroll
            for (int mi = 0; mi < 4; ++mi) af[mi] = *(const short8*)&As[a_base + mi * 512];
            #pragma unroll
            for (int ni = 0; ni < 4; ++ni) bf[ni] = *(const short8*)&Bs[b_base + ni * 512];
            #pragma unroll
            for (int mi = 0; mi < 4; ++mi)
                #pragma unroll
                for (int ni = 0; ni < 4; ++ni)
                    acc[mi][ni] = __builtin_amdgcn_mfma_f32_16x16x32_bf16(
                        af[mi], bf[ni], acc[mi][ni], 0, 0, 0);
            __syncthreads();
        }
    } else {
        // Cin == 256
        for (int c = 0; c < 8; ++c) {
            const int cb = c * 32;
            #pragma unroll 1
            for (int tap = 0; tap < 9; ++tap) {
                const int kA = tap * 256 + cb;
                gl_lds16(ag0 + kA, al0);
                gl_lds16(ag1 + kA, al1);
                const int dy = tap / 3 - 1;
                const int dx = tap - (tap / 3) * 3 - 1;
                const int yy = qy + dy, xx = qx + dx;
                const bool v = qin && yy >= 0 && yy < H && xx >= 0 && xx < Wd;
                const ushort* bg = v ? (Xn + (size_t)(yy * Wd + xx) * 256 + cb + kq8) : zp;
                gl_lds16(bg, bl);
                __syncthreads();
                short8 af[4], bf[4];
                #pragma unroll
                for (int mi = 0; mi < 4; ++mi) af[mi] = *(const short8*)&As[a_base + mi * 512];
                #pragma unroll
                for (int ni = 0; ni < 4; ++ni) bf[ni] = *(const short8*)&Bs[b_base + ni * 512];
                #pragma unroll
                for (int mi = 0; mi < 4; ++mi)
                    #pragma unroll
                    for (int ni = 0; ni < 4; ++ni)
                        acc[mi][ni] = __builtin_amdgcn_mfma_f32_16x16x32_bf16(
                            af[mi], bf[ni], acc[mi][ni], 0, 0, 0);
                __syncthreads();
            }
        }
    }

    const int wm = (wave >> 1) * 64;
    const int wn = (wave & 1) * 64;
    #pragma unroll
    for (int mi = 0; mi < 4; ++mi) {
        const int co = wm + mi * 16 + lq * 4;
        float4 bv = *(const float4*)&bias[co];
        float bb[4] = {bv.x, bv.y, bv.z, bv.w};
        #pragma unroll
        for (int ni = 0; ni < 4; ++ni) {
            const int q2 = p0 + wn + ni * 16 + l15;
            if (q2 < HW) {
                ushort4 h;
                h.x = f2bf(acc[mi][ni][0] + bb[0]);
                h.y = f2bf(acc[mi][ni][1] + bb[1]);
                h.z = f2bf(acc[mi][ni][2] + bb[2]);
                h.w = f2bf(acc[mi][ni][3] + bb[3]);
                *(ushort4*)&Yn[(size_t)q2 * 256 + co] = h;
            }
        }
    }
}

// ---------------- upsample(2x bilinear, half-pixel, clamp) + add, NHWC bf16 ----
__global__ void upsample_add_nhwc(ushort* __restrict__ T, const ushort* __restrict__ Pn,
                                  int H, int Wd, int total32)
{
    int i = blockIdx.x * 256 + threadIdx.x;
    if (i >= total32) return;
    const int cg = (i & 31) * 8;
    const int q  = i >> 5;
    const int HW = H * Wd;
    const int pix = q % HW;
    const int n   = q / HW;
    const int y = pix / Wd, x = pix - (pix / Wd) * Wd;
    const int Hh = H >> 1, Wh = Wd >> 1;

    float sy = fminf(fmaxf(y * 0.5f - 0.25f, 0.f), (float)(Hh - 1));
    float sx = fminf(fmaxf(x * 0.5f - 0.25f, 0.f), (float)(Wh - 1));
    int y0 = (int)sy, x0 = (int)sx;
    int y1 = min(y0 + 1, Hh - 1), x1 = min(x0 + 1, Wh - 1);
    float fy = sy - (float)y0, fx = sx - (float)x0;

    const ushort* base = Pn + (size_t)n * Hh * Wh * 256 + cg;
    ushort8v a00 = *(const ushort8v*)&base[(size_t)(y0 * Wh + x0) * 256];
    ushort8v a01 = *(const ushort8v*)&base[(size_t)(y0 * Wh + x1) * 256];
    ushort8v a10 = *(const ushort8v*)&base[(size_t)(y1 * Wh + x0) * 256];
    ushort8v a11 = *(const ushort8v*)&base[(size_t)(y1 * Wh + x1) * 256];

    ushort* tp = T + (size_t)q * 256 + cg;
    ushort8v tv = *(ushort8v*)tp;
    ushort8v r;
    #pragma unroll
    for (int j = 0; j < 8; ++j) {
        float v = (1.f - fy) * ((1.f - fx) * bf2f(a00[j]) + fx * bf2f(a01[j]))
                +        fy  * ((1.f - fx) * bf2f(a10[j]) + fx * bf2f(a11[j]));
        r[j] = f2bf(bf2f(tv[j]) + v);
    }
    *(ushort8v*)tp = r;
}

// ---------------- roi align (NHWC bf16 feats, f32 out) ----------------
__global__ __launch_bounds__(256) void roi_align_k(
    const float* __restrict__ rois, const float* __restrict__ im_info,
    const ushort* __restrict__ p2, const ushort* __restrict__ p3,
    const ushort* __restrict__ p4, const ushort* __restrict__ p5,
    float* __restrict__ out)
{
    const int r   = blockIdx.x;
    const int tid = threadIdx.x;

    __shared__ int   s_y0[14], s_y1[14], s_x0[14], s_x1[14];
    __shared__ float s_ly[14], s_lx[14], s_vy[14], s_vx[14];
    __shared__ float s_o[256 * 49];

    const float bx  = rois[r * 5 + 0];
    const float x1r = rois[r * 5 + 1];
    const float y1r = rois[r * 5 + 2];
    const float x2r = rois[r * 5 + 3];
    const float y2r = rois[r * 5 + 4];

    const float hh = y2r - y1r + 1.f;
    const float ww = x2r - x1r + 1.f;
    float lf = rintf(logf(sqrtf(hh * ww) * (1.f / 224.f)) + 4.f);
    lf = fminf(fmaxf(lf, 2.f), 5.f);
    const int lvl = (int)lf;

    const ushort* feat; int H, W;
    if      (lvl == 2) { feat = p2; H = 200; W = 304; }
    else if (lvl == 3) { feat = p3; H = 100; W = 152; }
    else if (lvl == 4) { feat = p4; H = 50;  W = 76;  }
    else               { feat = p5; H = 25;  W = 38;  }

    const float im_h  = im_info[0];
    const float scale = (float)H / im_h;
    const float x1 = x1r * scale, y1 = y1r * scale;
    const float x2 = x2r * scale, y2 = y2r * scale;
    const float rw = fmaxf(x2 - x1, 1.f);
    const float rh = fmaxf(y2 - y1, 1.f);
    const float bh = rh * (1.f / 7.f);
    const float bw = rw * (1.f / 7.f);

    if (tid < 28) {
        if (tid < 14) {
            int i = tid, pi = i >> 1, s = i & 1;
            float ys = y1 + pi * bh + (s + 0.5f) * bh * 0.5f;
            float v  = (ys >= -1.f && ys <= (float)H) ? 1.f : 0.f;
            float yc = fminf(fmaxf(ys, 0.f), (float)H - 1.f);
            int y0 = (int)floorf(yc);
            s_y0[i] = y0; s_y1[i] = min(y0 + 1, H - 1);
            s_ly[i] = yc - (float)y0; s_vy[i] = v;
        } else {
            int i = tid - 14, pi = i >> 1, s = i & 1;
            float xs = x1 + pi * bw + (s + 0.5f) * bw * 0.5f;
            float v  = (xs >= -1.f && xs <= (float)W) ? 1.f : 0.f;
            float xc = fminf(fmaxf(xs, 0.f), (float)W - 1.f);
            int x0 = (int)floorf(xc);
            s_x0[i] = x0; s_x1[i] = min(x0 + 1, W - 1);
            s_lx[i] = xc - (float)x0; s_vx[i] = v;
        }
    }
    __syncthreads();

    const int b = (int)bx;
    const ushort* fc = feat + (size_t)b * H * W * 256 + tid;

    #pragma unroll
    for (int py = 0; py < 7; ++py) {
        #pragma unroll
        for (int px = 0; px < 7; ++px) {
            float acc = 0.f;
            #pragma unroll
            for (int sy = 0; sy < 2; ++sy) {
                #pragma unroll
                for (int sx = 0; sx < 2; ++sx) {
                    int iy = py * 2 + sy, ix = px * 2 + sx;
                    float ly = s_ly[iy], lx = s_lx[ix];
                    float hy = 1.f - ly, hx = 1.f - lx;
                    int y0 = s_y0[iy], y1i = s_y1[iy];
                    int x0 = s_x0[ix], x1i = s_x1[ix];
                    float v00 = bf2f(fc[(size_t)(y0 * W + x0) * 256]);
                    float v01 = bf2f(fc[(size_t)(y0 * W + x1i) * 256]);
                    float v10 = bf2f(fc[(size_t)(y1i * W + x0) * 256]);
                    float v11 = bf2f(fc[(size_t)(y1i * W + x1i) * 256]);
                    float val = hy * hx * v00 + hy * lx * v01
                              + ly * hx * v10 + ly * lx * v11;
                    acc += val * s_vy[iy] * s_vx[ix];
                }
            }
            s_o[tid * 49 + py * 7 + px] = acc * 0.25f;
        }
    }
    __syncthreads();
    float* orow = out + (size_t)r * 256 * 49;
    for (int it = 0; it < 49; ++it)
        orow[it * 256 + tid] = s_o[it * 256 + tid];
}

static inline int cdiv(int a, int b) { return (a + b - 1) / b; }

extern "C" void kernel_launch(void* const* d_in, const int* in_sizes, int n_in,
                              void* d_out, int out_size, void* d_ws, size_t ws_size,
                              hipStream_t stream) {
    const float* c2      = (const float*)d_in[0];
    const float* c3      = (const float*)d_in[1];
    const float* c4      = (const float*)d_in[2];
    const float* c5      = (const float*)d_in[3];
    const float* rois    = (const float*)d_in[4];
    const float* im_info = (const float*)d_in[5];
    const float* w_top   = (const float*)d_in[6];
    const float* b_top   = (const float*)d_in[7];
    const float* w_lat1  = (const float*)d_in[8];
    const float* b_lat1  = (const float*)d_in[9];
    const float* w_lat2  = (const float*)d_in[10];
    const float* b_lat2  = (const float*)d_in[11];
    const float* w_lat3  = (const float*)d_in[12];
    const float* b_lat3  = (const float*)d_in[13];
    const float* w_sm1   = (const float*)d_in[14];
    const float* b_sm1   = (const float*)d_in[15];
    const float* w_sm2   = (const float*)d_in[16];
    const float* b_sm2   = (const float*)d_in[17];
    const float* w_sm3   = (const float*)d_in[18];
    const float* b_sm3   = (const float*)d_in[19];
    float* out = (float*)d_out;
    ushort* ws = (ushort*)d_ws;

    // workspace layout (bf16 elements, all offsets 16B-aligned)
    ushort* c2t = ws;                      // 2*60800*256 = 31129600
    ushort* c3t = c2t + 31129600;          // 2*15200*512 = 15564800
    ushort* c4t = c3t + 15564800;          // 2*3800*1024 = 7782400
    ushort* c5t = c4t + 7782400;           // 2*950*2048  = 3891200
    ushort* p5  = c5t + 3891200;           // 2*950*256   = 486400
    ushort* p4  = p5  + 486400;            // 2*3800*256  = 1945600
    ushort* p3  = p4  + 1945600;           // 2*15200*256 = 7782400
    ushort* p2  = p3  + 7782400;           // 2*60800*256 = 31129600
    ushort* T   = p2  + 31129600;          // scratch     = 31129600
    ushort* wtp = T   + 31129600;          // 256*2048
    ushort* wl1 = wtp + 524288;            // 256*1024
    ushort* wl2 = wl1 + 262144;            // 256*512
    ushort* wl3 = wl2 + 131072;            // 256*256
    ushort* ws1 = wl3 + 65536;             // 256*2304
    ushort* ws2 = ws1 + 589824;
    ushort* ws3 = ws2 + 589824;
    ushort* zp  = ws3 + 589824;            // 64B zero page

    // zero page for OOB global_load_lds lanes (d_ws is re-poisoned each call)
    hipMemsetAsync((void*)zp, 0, 64, stream);

    dim3 blk(256);
    dim3 cblk(512);

    // pack weights
    cast_k<<<cdiv(524288, 256), blk, 0, stream>>>(w_top,  wtp, 524288);
    cast_k<<<cdiv(262144, 256), blk, 0, stream>>>(w_lat1, wl1, 262144);
    cast_k<<<cdiv(131072, 256), blk, 0, stream>>>(w_lat2, wl2, 131072);
    cast_k<<<cdiv(65536,  256), blk, 0, stream>>>(w_lat3, wl3, 65536);
    pack_w3<<<cdiv(589824, 256), blk, 0, stream>>>(w_sm1, ws1, 256);
    pack_w3<<<cdiv(589824, 256), blk, 0, stream>>>(w_sm2, ws2, 256);
    pack_w3<<<cdiv(589824, 256), blk, 0, stream>>>(w_sm3, ws3, 256);

    // transpose inputs to NHWC bf16
    nchw2nhwc<<<dim3(1900, 8,  2), blk, 0, stream>>>(c2, c2t, 256,  60800);
    nchw2nhwc<<<dim3(475, 16,  2), blk, 0, stream>>>(c3, c3t, 512,  15200);
    nchw2nhwc<<<dim3(119, 32,  2), blk, 0, stream>>>(c4, c4t, 1024, 3800);
    nchw2nhwc<<<dim3(30,  64,  2), blk, 0, stream>>>(c5, c5t, 2048, 950);

    // p5 = conv1x1(c5)
    conv_mfma<1><<<dim3(8, 1, 2), cblk, 0, stream>>>(c5t, wtp, b_top, p5, zp, 2048, 25, 38);

    // level 4
    conv_mfma<1><<<dim3(30, 1, 2), cblk, 0, stream>>>(c4t, wl1, b_lat1, T, zp, 1024, 50, 76);
    upsample_add_nhwc<<<cdiv(2 * 3800 * 32, 256), blk, 0, stream>>>(T, p5, 50, 76, 2 * 3800 * 32);
    conv_mfma<9><<<dim3(30, 1, 2), cblk, 0, stream>>>(T, ws1, b_sm1, p4, zp, 256, 50, 76);

    // level 3
    conv_mfma<1><<<dim3(119, 1, 2), cblk, 0, stream>>>(c3t, wl2, b_lat2, T, zp, 512, 100, 152);
    upsample_add_nhwc<<<cdiv(2 * 15200 * 32, 256), blk, 0, stream>>>(T, p4, 100, 152, 2 * 15200 * 32);
    conv_mfma<9><<<dim3(119, 1, 2), cblk, 0, stream>>>(T, ws2, b_sm2, p3, zp, 256, 100, 152);

    // level 2
    conv_mfma<1><<<dim3(475, 1, 2), cblk, 0, stream>>>(c2t, wl3, b_lat3, T, zp, 256, 200, 304);
    upsample_add_nhwc<<<cdiv(2 * 60800 * 32, 256), blk, 0, stream>>>(T, p3, 200, 304, 2 * 60800 * 32);
    conv_mfma<9><<<dim3(475, 1, 2), cblk, 0, stream>>>(T, ws3, b_sm3, p2, zp, 256, 200, 304);

    // roi align
    roi_align_k<<<dim3(1024), blk, 0, stream>>>(rois, im_info, p2, p3, p4, p5, out);
}

// Round 4
// 1148.576 us; speedup vs baseline: 4.7801x; 1.0526x over previous
//
#include <hip/hip_runtime.h>
#include <math.h>

typedef __attribute__((ext_vector_type(8))) short short8;
typedef __attribute__((ext_vector_type(4))) float f32x4;
typedef __attribute__((ext_vector_type(8))) unsigned short ushort8v;

__device__ __forceinline__ ushort f2bf(float f) {
    unsigned u = __builtin_bit_cast(unsigned, f);
    u = (u + 0x7fffu + ((u >> 16) & 1u)) >> 16;
    return (ushort)u;
}
__device__ __forceinline__ float bf2f(ushort h) {
    unsigned u = ((unsigned)h) << 16;
    return __builtin_bit_cast(float, u);
}

// async 16B global->LDS: lane's data lands at ldsbase + lane*16
__device__ __forceinline__ void gl_lds16(const ushort* g, ushort* l) {
    __builtin_amdgcn_global_load_lds(
        (const __attribute__((address_space(1))) unsigned int*)g,
        (__attribute__((address_space(3))) unsigned int*)l, 16, 0, 0);
}

// ---------------- cast / pack kernels ----------------

__global__ void nchw2nhwc(const float* __restrict__ in, ushort* __restrict__ out,
                          int C, int HW)
{
    __shared__ float tile[32][33];
    const int n  = blockIdx.z;
    const int c0 = blockIdx.y * 32;
    const int p0 = blockIdx.x * 32;
    const float* inp = in + (size_t)n * C * HW;
    ushort* op = out + (size_t)n * HW * C;
    const int tx = threadIdx.x & 31, ty = threadIdx.x >> 5;
    #pragma unroll
    for (int i = 0; i < 4; ++i) {
        int c = ty + i * 8;
        int p = p0 + tx;
        tile[c][tx] = (p < HW) ? inp[(size_t)(c0 + c) * HW + p] : 0.f;
    }
    __syncthreads();
    #pragma unroll
    for (int i = 0; i < 4; ++i) {
        int p = ty + i * 8;
        if (p0 + p < HW) op[(size_t)(p0 + p) * C + c0 + tx] = f2bf(tile[tx][p]);
    }
}

__global__ void cast_k(const float* __restrict__ in, ushort* __restrict__ out, int n)
{
    int i = blockIdx.x * 256 + threadIdx.x;
    if (i < n) out[i] = f2bf(in[i]);
}

// 3x3 weights OIHW f32 -> [co][tap][ci] bf16 (tap-major K)
__global__ void pack_w3(const float* __restrict__ w, ushort* __restrict__ wp, int Cin)
{
    int i = blockIdx.x * 256 + threadIdx.x;
    int total = 256 * Cin * 9;
    if (i >= total) return;
    int co  = i / (9 * Cin);
    int rem = i - co * 9 * Cin;
    int tap = rem / Cin;
    int ci  = rem - tap * Cin;
    wp[i] = f2bf(w[(size_t)co * Cin * 9 + (size_t)ci * 9 + tap]);
}

// ---------------- MFMA conv (implicit GEMM, NHWC bf16) ----------------
// Block: 512 thr (8 waves), tile M=256 (all cout) x N=128 pixels, BK=32.
// Double-buffered LDS staging via global_load_lds(16B), ONE barrier per chunk:
//   barrier -> ds_read frags(buf par) -> prefetch chunk c+1 (buf par^1) -> MFMA.
// TAPS==9: chunk = (channel-chunk OUTER, tap INNER) for L2 reuse of X rows.
template<int TAPS>
__global__ __launch_bounds__(512, 2) void conv_mfma(
    const ushort* __restrict__ X, const ushort* __restrict__ Wp,
    const float* __restrict__ bias, ushort* __restrict__ Y,
    const ushort* __restrict__ zp,
    int Cin, int H, int Wd)
{
    const int HW   = H * Wd;
    const int Ktot = Cin * TAPS;
    const int n    = blockIdx.z;
    const int p0   = blockIdx.x * 128;
    const ushort* Xn = X + (size_t)n * HW * Cin;
    ushort* Yn       = Y + (size_t)n * HW * 256;

    const int t    = threadIdx.x;
    const int lane = t & 63;
    const int wave = t >> 6;            // 0..7
    const int l15  = lane & 15, lq = lane >> 4;
    const int kq8  = lq * 8;            // 16B chunk offset in k (shorts)

    __shared__ __align__(16) ushort As[2][8192];   // 256 rows x 32 k, x2
    __shared__ __align__(16) ushort Bs[2][4096];   // 128 rows x 32 k, x2

    const ushort* ag0 = Wp + (size_t)(wave * 32 + l15) * Ktot + kq8;
    const ushort* ag1 = ag0 + (size_t)16 * Ktot;

    const int q   = p0 + wave * 16 + l15;
    const bool qin = q < HW;
    int qy = 0, qx = 0;
    if (TAPS == 9) { qy = q / Wd; qx = q - qy * Wd; }

    // fragment read bases (shorts); wave-linear -> conflict-free
    const int a_base = ((wave >> 1) * 256 + lq * 16 + l15) * 8;
    const int b_base = ((wave & 1) * 256 + lq * 16 + l15) * 8;

    auto stage = [&](int c, int par) {
        int kA, cb;
        int dy = 0, dx = 0;
        if (TAPS == 1) {
            kA = c << 5; cb = kA;
        } else {
            unsigned cc = (unsigned)c;
            unsigned cidx = cc / 9u;
            unsigned tap  = cc - cidx * 9u;
            cb = (int)(cidx << 5);
            kA = (int)(tap * 256u) + cb;
            int t3 = (int)tap / 3;
            dy = t3 - 1;
            dx = (int)tap - t3 * 3 - 1;
        }
        gl_lds16(ag0 + kA, &As[par][(wave * 2 + 0) * 512]);
        gl_lds16(ag1 + kA, &As[par][(wave * 2 + 1) * 512]);
        const ushort* bg;
        if (TAPS == 1) {
            bg = qin ? (Xn + (size_t)q * Cin + cb + kq8) : zp;
        } else {
            int yy = qy + dy, xx = qx + dx;
            bool v = qin && yy >= 0 && yy < H && xx >= 0 && xx < Wd;
            bg = v ? (Xn + (size_t)(yy * Wd + xx) * 256 + cb + kq8) : zp;
        }
        gl_lds16(bg, &Bs[par][wave * 512]);
    };

    const int nch = (TAPS == 1) ? (Cin >> 5) : 72;
    f32x4 acc[4][4] = {};

    stage(0, 0);
    for (int c = 0; c < nch; ++c) {
        const int par = c & 1;
        __syncthreads();    // drains vmcnt: buf[par] data has arrived
        short8 af[4], bf[4];
        #pragma unroll
        for (int mi = 0; mi < 4; ++mi) af[mi] = *(const short8*)&As[par][a_base + mi * 512];
        #pragma unroll
        for (int ni = 0; ni < 4; ++ni) bf[ni] = *(const short8*)&Bs[par][b_base + ni * 512];
        if (c + 1 < nch) stage(c + 1, par ^ 1);
        #pragma unroll
        for (int mi = 0; mi < 4; ++mi)
            #pragma unroll
            for (int ni = 0; ni < 4; ++ni)
                acc[mi][ni] = __builtin_amdgcn_mfma_f32_16x16x32_bf16(
                    af[mi], bf[ni], acc[mi][ni], 0, 0, 0);
    }

    const int wm = (wave >> 1) * 64;
    const int wn = (wave & 1) * 64;
    #pragma unroll
    for (int mi = 0; mi < 4; ++mi) {
        const int co = wm + mi * 16 + lq * 4;
        float4 bv = *(const float4*)&bias[co];
        float bb[4] = {bv.x, bv.y, bv.z, bv.w};
        #pragma unroll
        for (int ni = 0; ni < 4; ++ni) {
            const int q2 = p0 + wn + ni * 16 + l15;
            if (q2 < HW) {
                ushort4 h;
                h.x = f2bf(acc[mi][ni][0] + bb[0]);
                h.y = f2bf(acc[mi][ni][1] + bb[1]);
                h.z = f2bf(acc[mi][ni][2] + bb[2]);
                h.w = f2bf(acc[mi][ni][3] + bb[3]);
                *(ushort4*)&Yn[(size_t)q2 * 256 + co] = h;
            }
        }
    }
}

// ---------------- upsample(2x bilinear, half-pixel, clamp) + add, NHWC bf16 ----
__global__ void upsample_add_nhwc(ushort* __restrict__ T, const ushort* __restrict__ Pn,
                                  int H, int Wd, int total32)
{
    int i = blockIdx.x * 256 + threadIdx.x;
    if (i >= total32) return;
    const int cg = (i & 31) * 8;
    const int q  = i >> 5;
    const int HW = H * Wd;
    const int pix = q % HW;
    const int n   = q / HW;
    const int y = pix / Wd, x = pix - (pix / Wd) * Wd;
    const int Hh = H >> 1, Wh = Wd >> 1;

    float sy = fminf(fmaxf(y * 0.5f - 0.25f, 0.f), (float)(Hh - 1));
    float sx = fminf(fmaxf(x * 0.5f - 0.25f, 0.f), (float)(Wh - 1));
    int y0 = (int)sy, x0 = (int)sx;
    int y1 = min(y0 + 1, Hh - 1), x1 = min(x0 + 1, Wh - 1);
    float fy = sy - (float)y0, fx = sx - (float)x0;

    const ushort* base = Pn + (size_t)n * Hh * Wh * 256 + cg;
    ushort8v a00 = *(const ushort8v*)&base[(size_t)(y0 * Wh + x0) * 256];
    ushort8v a01 = *(const ushort8v*)&base[(size_t)(y0 * Wh + x1) * 256];
    ushort8v a10 = *(const ushort8v*)&base[(size_t)(y1 * Wh + x0) * 256];
    ushort8v a11 = *(const ushort8v*)&base[(size_t)(y1 * Wh + x1) * 256];

    ushort* tp = T + (size_t)q * 256 + cg;
    ushort8v tv = *(ushort8v*)tp;
    ushort8v r;
    #pragma unroll
    for (int j = 0; j < 8; ++j) {
        float v = (1.f - fy) * ((1.f - fx) * bf2f(a00[j]) + fx * bf2f(a01[j]))
                +        fy  * ((1.f - fx) * bf2f(a10[j]) + fx * bf2f(a11[j]));
        r[j] = f2bf(bf2f(tv[j]) + v);
    }
    *(ushort8v*)tp = r;
}

// ---------------- roi align (NHWC bf16 feats, f32 out) ----------------
__global__ __launch_bounds__(256) void roi_align_k(
    const float* __restrict__ rois, const float* __restrict__ im_info,
    const ushort* __restrict__ p2, const ushort* __restrict__ p3,
    const ushort* __restrict__ p4, const ushort* __restrict__ p5,
    float* __restrict__ out)
{
    const int r   = blockIdx.x;
    const int tid = threadIdx.x;

    __shared__ int   s_y0[14], s_y1[14], s_x0[14], s_x1[14];
    __shared__ float s_ly[14], s_lx[14], s_vy[14], s_vx[14];
    __shared__ float s_o[256 * 49];

    const float bx  = rois[r * 5 + 0];
    const float x1r = rois[r * 5 + 1];
    const float y1r = rois[r * 5 + 2];
    const float x2r = rois[r * 5 + 3];
    const float y2r = rois[r * 5 + 4];

    const float hh = y2r - y1r + 1.f;
    const float ww = x2r - x1r + 1.f;
    float lf = rintf(logf(sqrtf(hh * ww) * (1.f / 224.f)) + 4.f);
    lf = fminf(fmaxf(lf, 2.f), 5.f);
    const int lvl = (int)lf;

    const ushort* feat; int H, W;
    if      (lvl == 2) { feat = p2; H = 200; W = 304; }
    else if (lvl == 3) { feat = p3; H = 100; W = 152; }
    else if (lvl == 4) { feat = p4; H = 50;  W = 76;  }
    else               { feat = p5; H = 25;  W = 38;  }

    const float im_h  = im_info[0];
    const float scale = (float)H / im_h;
    const float x1 = x1r * scale, y1 = y1r * scale;
    const float x2 = x2r * scale, y2 = y2r * scale;
    const float rw = fmaxf(x2 - x1, 1.f);
    const float rh = fmaxf(y2 - y1, 1.f);
    const float bh = rh * (1.f / 7.f);
    const float bw = rw * (1.f / 7.f);

    if (tid < 28) {
        if (tid < 14) {
            int i = tid, pi = i >> 1, s = i & 1;
            float ys = y1 + pi * bh + (s + 0.5f) * bh * 0.5f;
            float v  = (ys >= -1.f && ys <= (float)H) ? 1.f : 0.f;
            float yc = fminf(fmaxf(ys, 0.f), (float)H - 1.f);
            int y0 = (int)floorf(yc);
            s_y0[i] = y0; s_y1[i] = min(y0 + 1, H - 1);
            s_ly[i] = yc - (float)y0; s_vy[i] = v;
        } else {
            int i = tid - 14, pi = i >> 1, s = i & 1;
            float xs = x1 + pi * bw + (s + 0.5f) * bw * 0.5f;
            float v  = (xs >= -1.f && xs <= (float)W) ? 1.f : 0.f;
            float xc = fminf(fmaxf(xs, 0.f), (float)W - 1.f);
            int x0 = (int)floorf(xc);
            s_x0[i] = x0; s_x1[i] = min(x0 + 1, W - 1);
            s_lx[i] = xc - (float)x0; s_vx[i] = v;
        }
    }
    __syncthreads();

    const int b = (int)bx;
    const ushort* fc = feat + (size_t)b * H * W * 256 + tid;

    #pragma unroll
    for (int py = 0; py < 7; ++py) {
        #pragma unroll
        for (int px = 0; px < 7; ++px) {
            float acc = 0.f;
            #pragma unroll
            for (int sy = 0; sy < 2; ++sy) {
                #pragma unroll
                for (int sx = 0; sx < 2; ++sx) {
                    int iy = py * 2 + sy, ix = px * 2 + sx;
                    float ly = s_ly[iy], lx = s_lx[ix];
                    float hy = 1.f - ly, hx = 1.f - lx;
                    int y0 = s_y0[iy], y1i = s_y1[iy];
                    int x0 = s_x0[ix], x1i = s_x1[ix];
                    float v00 = bf2f(fc[(size_t)(y0 * W + x0) * 256]);
                    float v01 = bf2f(fc[(size_t)(y0 * W + x1i) * 256]);
                    float v10 = bf2f(fc[(size_t)(y1i * W + x0) * 256]);
                    float v11 = bf2f(fc[(size_t)(y1i * W + x1i) * 256]);
                    float val = hy * hx * v00 + hy * lx * v01
                              + ly * hx * v10 + ly * lx * v11;
                    acc += val * s_vy[iy] * s_vx[ix];
                }
            }
            s_o[tid * 49 + py * 7 + px] = acc * 0.25f;
        }
    }
    __syncthreads();
    float* orow = out + (size_t)r * 256 * 49;
    for (int it = 0; it < 49; ++it)
        orow[it * 256 + tid] = s_o[it * 256 + tid];
}

static inline int cdiv(int a, int b) { return (a + b - 1) / b; }

extern "C" void kernel_launch(void* const* d_in, const int* in_sizes, int n_in,
                              void* d_out, int out_size, void* d_ws, size_t ws_size,
                              hipStream_t stream) {
    const float* c2      = (const float*)d_in[0];
    const float* c3      = (const float*)d_in[1];
    const float* c4      = (const float*)d_in[2];
    const float* c5      = (const float*)d_in[3];
    const float* rois    = (const float*)d_in[4];
    const float* im_info = (const float*)d_in[5];
    const float* w_top   = (const float*)d_in[6];
    const float* b_top   = (const float*)d_in[7];
    const float* w_lat1  = (const float*)d_in[8];
    const float* b_lat1  = (const float*)d_in[9];
    const float* w_lat2  = (const float*)d_in[10];
    const float* b_lat2  = (const float*)d_in[11];
    const float* w_lat3  = (const float*)d_in[12];
    const float* b_lat3  = (const float*)d_in[13];
    const float* w_sm1   = (const float*)d_in[14];
    const float* b_sm1   = (const float*)d_in[15];
    const float* w_sm2   = (const float*)d_in[16];
    const float* b_sm2   = (const float*)d_in[17];
    const float* w_sm3   = (const float*)d_in[18];
    const float* b_sm3   = (const float*)d_in[19];
    float* out = (float*)d_out;
    ushort* ws = (ushort*)d_ws;

    // workspace layout (bf16 elements, all offsets 16B-aligned)
    ushort* c2t = ws;                      // 2*60800*256 = 31129600
    ushort* c3t = c2t + 31129600;          // 2*15200*512 = 15564800
    ushort* c4t = c3t + 15564800;          // 2*3800*1024 = 7782400
    ushort* c5t = c4t + 7782400;           // 2*950*2048  = 3891200
    ushort* p5  = c5t + 3891200;           // 2*950*256   = 486400
    ushort* p4  = p5  + 486400;            // 2*3800*256  = 1945600
    ushort* p3  = p4  + 1945600;           // 2*15200*256 = 7782400
    ushort* p2  = p3  + 7782400;           // 2*60800*256 = 31129600
    ushort* T   = p2  + 31129600;          // scratch     = 31129600
    ushort* wtp = T   + 31129600;          // 256*2048
    ushort* wl1 = wtp + 524288;            // 256*1024
    ushort* wl2 = wl1 + 262144;            // 256*512
    ushort* wl3 = wl2 + 131072;            // 256*256
    ushort* ws1 = wl3 + 65536;             // 256*2304
    ushort* ws2 = ws1 + 589824;
    ushort* ws3 = ws2 + 589824;
    ushort* zp  = ws3 + 589824;            // 64B zero page

    // zero page for OOB global_load_lds lanes (d_ws is re-poisoned each call)
    hipMemsetAsync((void*)zp, 0, 64, stream);

    dim3 blk(256);
    dim3 cblk(512);

    // pack weights
    cast_k<<<cdiv(524288, 256), blk, 0, stream>>>(w_top,  wtp, 524288);
    cast_k<<<cdiv(262144, 256), blk, 0, stream>>>(w_lat1, wl1, 262144);
    cast_k<<<cdiv(131072, 256), blk, 0, stream>>>(w_lat2, wl2, 131072);
    cast_k<<<cdiv(65536,  256), blk, 0, stream>>>(w_lat3, wl3, 65536);
    pack_w3<<<cdiv(589824, 256), blk, 0, stream>>>(w_sm1, ws1, 256);
    pack_w3<<<cdiv(589824, 256), blk, 0, stream>>>(w_sm2, ws2, 256);
    pack_w3<<<cdiv(589824, 256), blk, 0, stream>>>(w_sm3, ws3, 256);

    // transpose inputs to NHWC bf16
    nchw2nhwc<<<dim3(1900, 8,  2), blk, 0, stream>>>(c2, c2t, 256,  60800);
    nchw2nhwc<<<dim3(475, 16,  2), blk, 0, stream>>>(c3, c3t, 512,  15200);
    nchw2nhwc<<<dim3(119, 32,  2), blk, 0, stream>>>(c4, c4t, 1024, 3800);
    nchw2nhwc<<<dim3(30,  64,  2), blk, 0, stream>>>(c5, c5t, 2048, 950);

    // p5 = conv1x1(c5)
    conv_mfma<1><<<dim3(8, 1, 2), cblk, 0, stream>>>(c5t, wtp, b_top, p5, zp, 2048, 25, 38);

    // level 4
    conv_mfma<1><<<dim3(30, 1, 2), cblk, 0, stream>>>(c4t, wl1, b_lat1, T, zp, 1024, 50, 76);
    upsample_add_nhwc<<<cdiv(2 * 3800 * 32, 256), blk, 0, stream>>>(T, p5, 50, 76, 2 * 3800 * 32);
    conv_mfma<9><<<dim3(30, 1, 2), cblk, 0, stream>>>(T, ws1, b_sm1, p4, zp, 256, 50, 76);

    // level 3
    conv_mfma<1><<<dim3(119, 1, 2), cblk, 0, stream>>>(c3t, wl2, b_lat2, T, zp, 512, 100, 152);
    upsample_add_nhwc<<<cdiv(2 * 15200 * 32, 256), blk, 0, stream>>>(T, p4, 100, 152, 2 * 15200 * 32);
    conv_mfma<9><<<dim3(119, 1, 2), cblk, 0, stream>>>(T, ws2, b_sm2, p3, zp, 256, 100, 152);

    // level 2
    conv_mfma<1><<<dim3(475, 1, 2), cblk, 0, stream>>>(c2t, wl3, b_lat3, T, zp, 256, 200, 304);
    upsample_add_nhwc<<<cdiv(2 * 60800 * 32, 256), blk, 0, stream>>>(T, p3, 200, 304, 2 * 60800 * 32);
    conv_mfma<9><<<dim3(475, 1, 2), cblk, 0, stream>>>(T, ws3, b_sm3, p2, zp, 256, 200, 304);

    // roi align
    roi_align_k<<<dim3(1024), blk, 0, stream>>>(rois, im_info, p2, p3, p4, p5, out);
}

// Round 5
// 1111.961 us; speedup vs baseline: 4.9375x; 1.0329x over previous
//
#include <hip/hip_runtime.h>
#include <math.h>

typedef __attribute__((ext_vector_type(8))) short short8;
typedef __attribute__((ext_vector_type(4))) float f32x4;
typedef __attribute__((ext_vector_type(8))) unsigned short ushort8v;

__device__ __forceinline__ ushort f2bf(float f) {
    unsigned u = __builtin_bit_cast(unsigned, f);
    u = (u + 0x7fffu + ((u >> 16) & 1u)) >> 16;
    return (ushort)u;
}
__device__ __forceinline__ float bf2f(ushort h) {
    unsigned u = ((unsigned)h) << 16;
    return __builtin_bit_cast(float, u);
}

// raw workgroup barrier WITHOUT vmcnt drain: own LDS ops drained (lgkm), but
// global->VGPR prefetch loads stay in flight across it (hipBLASLt pattern).
__device__ __forceinline__ void wg_barrier() {
    asm volatile("s_waitcnt lgkmcnt(0)\n\ts_barrier" ::: "memory");
}

// ---------------- cast / pack kernels ----------------

__global__ void nchw2nhwc(const float* __restrict__ in, ushort* __restrict__ out,
                          int C, int HW)
{
    __shared__ float tile[32][33];
    const int n  = blockIdx.z;
    const int c0 = blockIdx.y * 32;
    const int p0 = blockIdx.x * 32;
    const float* inp = in + (size_t)n * C * HW;
    ushort* op = out + (size_t)n * HW * C;
    const int tx = threadIdx.x & 31, ty = threadIdx.x >> 5;
    #pragma unroll
    for (int i = 0; i < 4; ++i) {
        int c = ty + i * 8;
        int p = p0 + tx;
        tile[c][tx] = (p < HW) ? inp[(size_t)(c0 + c) * HW + p] : 0.f;
    }
    __syncthreads();
    #pragma unroll
    for (int i = 0; i < 4; ++i) {
        int p = ty + i * 8;
        if (p0 + p < HW) op[(size_t)(p0 + p) * C + c0 + tx] = f2bf(tile[tx][p]);
    }
}

__global__ void cast_k(const float* __restrict__ in, ushort* __restrict__ out, int n)
{
    int i = blockIdx.x * 256 + threadIdx.x;
    if (i < n) out[i] = f2bf(in[i]);
}

// 3x3 weights OIHW f32 -> [co][tap][ci] bf16 (tap-major K)
__global__ void pack_w3(const float* __restrict__ w, ushort* __restrict__ wp, int Cin)
{
    int i = blockIdx.x * 256 + threadIdx.x;
    int total = 256 * Cin * 9;
    if (i >= total) return;
    int co  = i / (9 * Cin);
    int rem = i - co * 9 * Cin;
    int tap = rem / Cin;
    int ci  = rem - tap * Cin;
    wp[i] = f2bf(w[(size_t)co * Cin * 9 + (size_t)ci * 9 + tap]);
}

// ---------------- MFMA conv (implicit GEMM, NHWC bf16) ----------------
// 256 threads (4 waves). Tile M=128 x N=128, BK=32. Software pipeline:
//   prefetch chunk c+2 global->VGPR (distance 2, 2 reg sets),
//   ds_write chunk c+1 VGPR->LDS[other buf]  (compiler emits PRECISE vmcnt wait),
//   raw s_barrier with lgkm-only drain -> loads live across barriers.
// LDS layout: chunk buf = As(128x32) | Bs(128x32); staging thread t writes at
// t*16B (lane-linear, conflict-free) == rowblk/l15/lq fragment layout.
template<int TAPS>
__global__ __launch_bounds__(256, 3) void conv_mfma(
    const ushort* __restrict__ X, const ushort* __restrict__ Wp,
    const float* __restrict__ bias, ushort* __restrict__ Y,
    int Cin, int H, int Wd)
{
    const int HW   = H * Wd;
    const int Ktot = Cin * TAPS;
    const int n    = blockIdx.z;
    const int p0   = blockIdx.x * 128;
    const int m0   = blockIdx.y * 128;
    const ushort* Xn = X + (size_t)n * HW * Cin;
    ushort* Yn       = Y + (size_t)n * HW * 256;

    const int t    = threadIdx.x;
    const int lane = t & 63;
    const int wave = t >> 6;            // 0..3
    const int l15  = lane & 15, lq = lane >> 4;

    __shared__ __align__(16) ushort smem[17408]; // 2 bufs x 8192 | epilogue 128x136

    // staging mapping: thread t <-> row r = (t>>6)*16 + (t&15), k-off ((t>>4)&3)*8
    const int rA  = ((t >> 6) << 4) | (t & 15);
    const int lq8 = ((t >> 4) & 3) * 8;
    const ushort* agA = Wp + (size_t)(m0 + rA) * Ktot + lq8;
    const ushort* agB = agA + (size_t)64 * Ktot;

    const int qa = p0 + rA, qb = qa + 64;
    int qay = 0, qax = 0, qby = 0, qbx = 0;
    if (TAPS == 9) {
        qay = qa / Wd; qax = qa - qay * Wd;
        qby = qb / Wd; qbx = qb - qby * Wd;
    }

    const int fr   = (lq * 16 + l15) * 8;
    const int aoff = ((wave >> 1) * 4) * 512;
    const int boff = 4096 + ((wave & 1) * 4) * 512;

    const int nch = (TAPS == 1) ? (Cin >> 5) : 72;

    // chunk loader: global -> 4 uint4 regs
    auto ld = [&](int c, uint4& a0, uint4& a1, uint4& b0, uint4& b1) {
        int kA, cb, dy = 0, dx = 0;
        if (TAPS == 1) {
            kA = c << 5; cb = kA;
        } else {
            int cidx = c / 9;
            int tap  = c - cidx * 9;
            int t3   = tap / 3;
            cb = cidx << 5;
            kA = tap * 256 + cb;
            dy = t3 - 1;
            dx = tap - t3 * 3 - 1;
        }
        a0 = *(const uint4*)(agA + kA);
        a1 = *(const uint4*)(agB + kA);
        if (TAPS == 1) {
            b0 = *(const uint4*)(Xn + (size_t)qa * Cin + cb + lq8);
            b1 = *(const uint4*)(Xn + (size_t)qb * Cin + cb + lq8);
        } else {
            int y0 = qay + dy, x0 = qax + dx;
            int y1 = qby + dy, x1 = qbx + dx;
            b0 = uint4{0u, 0u, 0u, 0u};
            b1 = uint4{0u, 0u, 0u, 0u};
            if (y0 >= 0 && y0 < H && x0 >= 0 && x0 < Wd)
                b0 = *(const uint4*)(Xn + (size_t)(y0 * Wd + x0) * 256 + cb + lq8);
            if (y1 >= 0 && y1 < H && x1 >= 0 && x1 < Wd)
                b1 = *(const uint4*)(Xn + (size_t)(y1 * Wd + x1) * 256 + cb + lq8);
        }
    };
    auto st = [&](int bb, const uint4& a0, const uint4& a1,
                  const uint4& b0, const uint4& b1) {
        *(uint4*)&smem[bb + t * 8]        = a0;
        *(uint4*)&smem[bb + 2048 + t * 8] = a1;
        *(uint4*)&smem[bb + 4096 + t * 8] = b0;
        *(uint4*)&smem[bb + 6144 + t * 8] = b1;
    };

    f32x4 acc[4][4] = {};
    uint4 a0_0, a1_0, b0_0, b1_0;   // set 0
    uint4 a0_1, a1_1, b0_1, b1_1;   // set 1

    ld(0, a0_0, a1_0, b0_0, b1_0);
    ld(1, a0_1, a1_1, b0_1, b1_1);
    st(0, a0_0, a1_0, b0_0, b1_0);
    wg_barrier();

    #pragma unroll 1
    for (int c = 0; c < nch; c += 2) {
        // ---- even chunk c: data in buf0 ----
        {
            short8 af[4], bf[4];
            #pragma unroll
            for (int mi = 0; mi < 4; ++mi) af[mi] = *(const short8*)&smem[aoff + mi * 512 + fr];
            #pragma unroll
            for (int ni = 0; ni < 4; ++ni) bf[ni] = *(const short8*)&smem[boff + ni * 512 + fr];
            st(8192, a0_1, a1_1, b0_1, b1_1);     // chunk c+1 -> buf1 (precise vmcnt wait)
            int cc = c + 2; if (cc >= nch) cc = nch - 1;
            ld(cc, a0_0, a1_0, b0_0, b1_0);       // prefetch chunk c+2
            #pragma unroll
            for (int mi = 0; mi < 4; ++mi)
                #pragma unroll
                for (int ni = 0; ni < 4; ++ni)
                    acc[mi][ni] = __builtin_amdgcn_mfma_f32_16x16x32_bf16(
                        af[mi], bf[ni], acc[mi][ni], 0, 0, 0);
            wg_barrier();
        }
        // ---- odd chunk c+1: data in buf1 ----
        {
            short8 af[4], bf[4];
            #pragma unroll
            for (int mi = 0; mi < 4; ++mi) af[mi] = *(const short8*)&smem[8192 + aoff + mi * 512 + fr];
            #pragma unroll
            for (int ni = 0; ni < 4; ++ni) bf[ni] = *(const short8*)&smem[8192 + boff + ni * 512 + fr];
            st(0, a0_0, a1_0, b0_0, b1_0);        // chunk c+2 -> buf0
            int cc = c + 3; if (cc >= nch) cc = nch - 1;
            ld(cc, a0_1, a1_1, b0_1, b1_1);       // prefetch chunk c+3
            #pragma unroll
            for (int mi = 0; mi < 4; ++mi)
                #pragma unroll
                for (int ni = 0; ni < 4; ++ni)
                    acc[mi][ni] = __builtin_amdgcn_mfma_f32_16x16x32_bf16(
                        af[mi], bf[ni], acc[mi][ni], 0, 0, 0);
            wg_barrier();
        }
    }

    // ---- epilogue: stage through LDS for 256B-contiguous global stores ----
    __syncthreads();
    const int wm = (wave >> 1) * 64, wn = (wave & 1) * 64;
    #pragma unroll
    for (int mi = 0; mi < 4; ++mi) {
        const int co = wm + mi * 16 + lq * 4;
        float4 bv = *(const float4*)&bias[m0 + co];
        float bb[4] = {bv.x, bv.y, bv.z, bv.w};
        #pragma unroll
        for (int ni = 0; ni < 4; ++ni) {
            const int p = wn + ni * 16 + l15;
            ushort4 h;
            h.x = f2bf(acc[mi][ni][0] + bb[0]);
            h.y = f2bf(acc[mi][ni][1] + bb[1]);
            h.z = f2bf(acc[mi][ni][2] + bb[2]);
            h.w = f2bf(acc[mi][ni][3] + bb[3]);
            *(ushort4*)&smem[p * 136 + co] = h;
        }
    }
    __syncthreads();
    #pragma unroll
    for (int it = 0; it < 8; ++it) {
        int idx = it * 256 + t;
        int px  = idx >> 4;
        int off = (idx & 15) * 8;
        int qq  = p0 + px;
        if (qq < HW)
            *(uint4*)&Yn[(size_t)qq * 256 + m0 + off] = *(const uint4*)&smem[px * 136 + off];
    }
}

// ---------------- upsample(2x bilinear, half-pixel, clamp) + add, NHWC bf16 ----
__global__ void upsample_add_nhwc(ushort* __restrict__ T, const ushort* __restrict__ Pn,
                                  int H, int Wd, int total32)
{
    int i = blockIdx.x * 256 + threadIdx.x;
    if (i >= total32) return;
    const int cg = (i & 31) * 8;
    const int q  = i >> 5;
    const int HW = H * Wd;
    const int pix = q % HW;
    const int n   = q / HW;
    const int y = pix / Wd, x = pix - (pix / Wd) * Wd;
    const int Hh = H >> 1, Wh = Wd >> 1;

    float sy = fminf(fmaxf(y * 0.5f - 0.25f, 0.f), (float)(Hh - 1));
    float sx = fminf(fmaxf(x * 0.5f - 0.25f, 0.f), (float)(Wh - 1));
    int y0 = (int)sy, x0 = (int)sx;
    int y1 = min(y0 + 1, Hh - 1), x1 = min(x0 + 1, Wh - 1);
    float fy = sy - (float)y0, fx = sx - (float)x0;

    const ushort* base = Pn + (size_t)n * Hh * Wh * 256 + cg;
    ushort8v a00 = *(const ushort8v*)&base[(size_t)(y0 * Wh + x0) * 256];
    ushort8v a01 = *(const ushort8v*)&base[(size_t)(y0 * Wh + x1) * 256];
    ushort8v a10 = *(const ushort8v*)&base[(size_t)(y1 * Wh + x0) * 256];
    ushort8v a11 = *(const ushort8v*)&base[(size_t)(y1 * Wh + x1) * 256];

    ushort* tp = T + (size_t)q * 256 + cg;
    ushort8v tv = *(ushort8v*)tp;
    ushort8v r;
    #pragma unroll
    for (int j = 0; j < 8; ++j) {
        float v = (1.f - fy) * ((1.f - fx) * bf2f(a00[j]) + fx * bf2f(a01[j]))
                +        fy  * ((1.f - fx) * bf2f(a10[j]) + fx * bf2f(a11[j]));
        r[j] = f2bf(bf2f(tv[j]) + v);
    }
    *(ushort8v*)tp = r;
}

// ---------------- roi align (NHWC bf16 feats, f32 out) ----------------
__global__ __launch_bounds__(256) void roi_align_k(
    const float* __restrict__ rois, const float* __restrict__ im_info,
    const ushort* __restrict__ p2, const ushort* __restrict__ p3,
    const ushort* __restrict__ p4, const ushort* __restrict__ p5,
    float* __restrict__ out)
{
    const int r   = blockIdx.x;
    const int tid = threadIdx.x;

    __shared__ int   s_y0[14], s_y1[14], s_x0[14], s_x1[14];
    __shared__ float s_ly[14], s_lx[14], s_vy[14], s_vx[14];
    __shared__ float s_o[256 * 49];

    const float bx  = rois[r * 5 + 0];
    const float x1r = rois[r * 5 + 1];
    const float y1r = rois[r * 5 + 2];
    const float x2r = rois[r * 5 + 3];
    const float y2r = rois[r * 5 + 4];

    const float hh = y2r - y1r + 1.f;
    const float ww = x2r - x1r + 1.f;
    float lf = rintf(logf(sqrtf(hh * ww) * (1.f / 224.f)) + 4.f);
    lf = fminf(fmaxf(lf, 2.f), 5.f);
    const int lvl = (int)lf;

    const ushort* feat; int H, W;
    if      (lvl == 2) { feat = p2; H = 200; W = 304; }
    else if (lvl == 3) { feat = p3; H = 100; W = 152; }
    else if (lvl == 4) { feat = p4; H = 50;  W = 76;  }
    else               { feat = p5; H = 25;  W = 38;  }

    const float im_h  = im_info[0];
    const float scale = (float)H / im_h;
    const float x1 = x1r * scale, y1 = y1r * scale;
    const float x2 = x2r * scale, y2 = y2r * scale;
    const float rw = fmaxf(x2 - x1, 1.f);
    const float rh = fmaxf(y2 - y1, 1.f);
    const float bh = rh * (1.f / 7.f);
    const float bw = rw * (1.f / 7.f);

    if (tid < 28) {
        if (tid < 14) {
            int i = tid, pi = i >> 1, s = i & 1;
            float ys = y1 + pi * bh + (s + 0.5f) * bh * 0.5f;
            float v  = (ys >= -1.f && ys <= (float)H) ? 1.f : 0.f;
            float yc = fminf(fmaxf(ys, 0.f), (float)H - 1.f);
            int y0 = (int)floorf(yc);
            s_y0[i] = y0; s_y1[i] = min(y0 + 1, H - 1);
            s_ly[i] = yc - (float)y0; s_vy[i] = v;
        } else {
            int i = tid - 14, pi = i >> 1, s = i & 1;
            float xs = x1 + pi * bw + (s + 0.5f) * bw * 0.5f;
            float v  = (xs >= -1.f && xs <= (float)W) ? 1.f : 0.f;
            float xc = fminf(fmaxf(xs, 0.f), (float)W - 1.f);
            int x0 = (int)floorf(xc);
            s_x0[i] = x0; s_x1[i] = min(x0 + 1, W - 1);
            s_lx[i] = xc - (float)x0; s_vx[i] = v;
        }
    }
    __syncthreads();

    const int b = (int)bx;
    const ushort* fc = feat + (size_t)b * H * W * 256 + tid;

    #pragma unroll
    for (int py = 0; py < 7; ++py) {
        #pragma unroll
        for (int px = 0; px < 7; ++px) {
            float acc = 0.f;
            #pragma unroll
            for (int sy = 0; sy < 2; ++sy) {
                #pragma unroll
                for (int sx = 0; sx < 2; ++sx) {
                    int iy = py * 2 + sy, ix = px * 2 + sx;
                    float ly = s_ly[iy], lx = s_lx[ix];
                    float hy = 1.f - ly, hx = 1.f - lx;
                    int y0 = s_y0[iy], y1i = s_y1[iy];
                    int x0 = s_x0[ix], x1i = s_x1[ix];
                    float v00 = bf2f(fc[(size_t)(y0 * W + x0) * 256]);
                    float v01 = bf2f(fc[(size_t)(y0 * W + x1i) * 256]);
                    float v10 = bf2f(fc[(size_t)(y1i * W + x0) * 256]);
                    float v11 = bf2f(fc[(size_t)(y1i * W + x1i) * 256]);
                    float val = hy * hx * v00 + hy * lx * v01
                              + ly * hx * v10 + ly * lx * v11;
                    acc += val * s_vy[iy] * s_vx[ix];
                }
            }
            s_o[tid * 49 + py * 7 + px] = acc * 0.25f;
        }
    }
    __syncthreads();
    float* orow = out + (size_t)r * 256 * 49;
    for (int it = 0; it < 49; ++it)
        orow[it * 256 + tid] = s_o[it * 256 + tid];
}

static inline int cdiv(int a, int b) { return (a + b - 1) / b; }

extern "C" void kernel_launch(void* const* d_in, const int* in_sizes, int n_in,
                              void* d_out, int out_size, void* d_ws, size_t ws_size,
                              hipStream_t stream) {
    const float* c2      = (const float*)d_in[0];
    const float* c3      = (const float*)d_in[1];
    const float* c4      = (const float*)d_in[2];
    const float* c5      = (const float*)d_in[3];
    const float* rois    = (const float*)d_in[4];
    const float* im_info = (const float*)d_in[5];
    const float* w_top   = (const float*)d_in[6];
    const float* b_top   = (const float*)d_in[7];
    const float* w_lat1  = (const float*)d_in[8];
    const float* b_lat1  = (const float*)d_in[9];
    const float* w_lat2  = (const float*)d_in[10];
    const float* b_lat2  = (const float*)d_in[11];
    const float* w_lat3  = (const float*)d_in[12];
    const float* b_lat3  = (const float*)d_in[13];
    const float* w_sm1   = (const float*)d_in[14];
    const float* b_sm1   = (const float*)d_in[15];
    const float* w_sm2   = (const float*)d_in[16];
    const float* b_sm2   = (const float*)d_in[17];
    const float* w_sm3   = (const float*)d_in[18];
    const float* b_sm3   = (const float*)d_in[19];
    float* out = (float*)d_out;
    ushort* ws = (ushort*)d_ws;

    // workspace layout (bf16 elements, all offsets 16B-aligned)
    ushort* c2t = ws;                      // 2*60800*256 = 31129600
    ushort* c3t = c2t + 31129600;          // 2*15200*512 = 15564800
    ushort* c4t = c3t + 15564800;          // 2*3800*1024 = 7782400
    ushort* c5t = c4t + 7782400;           // 2*950*2048  = 3891200
    ushort* p5  = c5t + 3891200;           // 2*950*256   = 486400
    ushort* p4  = p5  + 486400;            // 2*3800*256  = 1945600
    ushort* p3  = p4  + 1945600;           // 2*15200*256 = 7782400
    ushort* p2  = p3  + 7782400;           // 2*60800*256 = 31129600
    ushort* T   = p2  + 31129600;          // scratch     = 31129600
    ushort* wtp = T   + 31129600;          // 256*2048
    ushort* wl1 = wtp + 524288;            // 256*1024
    ushort* wl2 = wl1 + 262144;            // 256*512
    ushort* wl3 = wl2 + 131072;            // 256*256
    ushort* ws1 = wl3 + 65536;             // 256*2304
    ushort* ws2 = ws1 + 589824;
    ushort* ws3 = ws2 + 589824;

    dim3 blk(256);

    // pack weights
    cast_k<<<cdiv(524288, 256), blk, 0, stream>>>(w_top,  wtp, 524288);
    cast_k<<<cdiv(262144, 256), blk, 0, stream>>>(w_lat1, wl1, 262144);
    cast_k<<<cdiv(131072, 256), blk, 0, stream>>>(w_lat2, wl2, 131072);
    cast_k<<<cdiv(65536,  256), blk, 0, stream>>>(w_lat3, wl3, 65536);
    pack_w3<<<cdiv(589824, 256), blk, 0, stream>>>(w_sm1, ws1, 256);
    pack_w3<<<cdiv(589824, 256), blk, 0, stream>>>(w_sm2, ws2, 256);
    pack_w3<<<cdiv(589824, 256), blk, 0, stream>>>(w_sm3, ws3, 256);

    // transpose inputs to NHWC bf16
    nchw2nhwc<<<dim3(1900, 8,  2), blk, 0, stream>>>(c2, c2t, 256,  60800);
    nchw2nhwc<<<dim3(475, 16,  2), blk, 0, stream>>>(c3, c3t, 512,  15200);
    nchw2nhwc<<<dim3(119, 32,  2), blk, 0, stream>>>(c4, c4t, 1024, 3800);
    nchw2nhwc<<<dim3(30,  64,  2), blk, 0, stream>>>(c5, c5t, 2048, 950);

    // p5 = conv1x1(c5)
    conv_mfma<1><<<dim3(8, 2, 2), blk, 0, stream>>>(c5t, wtp, b_top, p5, 2048, 25, 38);

    // level 4
    conv_mfma<1><<<dim3(30, 2, 2), blk, 0, stream>>>(c4t, wl1, b_lat1, T, 1024, 50, 76);
    upsample_add_nhwc<<<cdiv(2 * 3800 * 32, 256), blk, 0, stream>>>(T, p5, 50, 76, 2 * 3800 * 32);
    conv_mfma<9><<<dim3(30, 2, 2), blk, 0, stream>>>(T, ws1, b_sm1, p4, 256, 50, 76);

    // level 3
    conv_mfma<1><<<dim3(119, 2, 2), blk, 0, stream>>>(c3t, wl2, b_lat2, T, 512, 100, 152);
    upsample_add_nhwc<<<cdiv(2 * 15200 * 32, 256), blk, 0, stream>>>(T, p4, 100, 152, 2 * 15200 * 32);
    conv_mfma<9><<<dim3(119, 2, 2), blk, 0, stream>>>(T, ws2, b_sm2, p3, 256, 100, 152);

    // level 2
    conv_mfma<1><<<dim3(475, 2, 2), blk, 0, stream>>>(c2t, wl3, b_lat3, T, 256, 200, 304);
    upsample_add_nhwc<<<cdiv(2 * 60800 * 32, 256), blk, 0, stream>>>(T, p3, 200, 304, 2 * 60800 * 32);
    conv_mfma<9><<<dim3(475, 2, 2), blk, 0, stream>>>(T, ws3, b_sm3, p2, 256, 200, 304);

    // roi align
    roi_align_k<<<dim3(1024), blk, 0, stream>>>(rois, im_info, p2, p3, p4, p5, out);
}